// Round 4
// baseline (160.263 us; speedup 1.0000x reference)
//
#include <hip/hip_runtime.h>

typedef __attribute__((ext_vector_type(8))) short short8;
typedef __attribute__((ext_vector_type(4))) float f32x4;

#define ROWS 16384   // B*N
#define DIM 64
#define NCODES 8192
#define MARGIN 0.008f
#define KT_FB 256
#define CTS_PER_BLOCK 32   // 512 codes per y-block -> 16 y-blocks -> 4 blocks/CU

// ws layout (bytes)
#define WS_BEST   0            // 16384 * 8
#define WS_COUNTS 131072       // 8192 * 4
#define WS_ENH    163840       // 8192 * 4
#define WS_ESWZ   196608       // 8192*64*2 terms * 2B = 2097152
#define WS_NEED   2293760

__device__ __forceinline__ unsigned long long pack_score(float s, int idx) {
  unsigned u = __float_as_uint(s);
  u ^= (unsigned)((int)u >> 31) | 0x80000000u;
  return ((unsigned long long)u << 32) | (unsigned)(0xFFFF - idx);
}
__device__ __forceinline__ unsigned short bf16hi(float f) {
  unsigned u = __float_as_uint(f);
  return (unsigned short)((u + 0x7FFFu + ((u >> 16) & 1u)) >> 16);
}

__global__ void vq_enorm(const float* __restrict__ embed, float* __restrict__ enh) {
  int k = blockIdx.x * 256 + threadIdx.x;
  const float4* e4 = (const float4*)(embed + (size_t)k * DIM);
  float a = 0.f, b = 0.f, c = 0.f, d = 0.f;
#pragma unroll
  for (int i = 0; i < DIM / 4; ++i) {
    float4 v = e4[i];
    a = fmaf(v.x, v.x, a); b = fmaf(v.y, v.y, b);
    c = fmaf(v.z, v.z, c); d = fmaf(v.w, v.w, d);
  }
  enh[k] = 0.5f * ((a + b) + (c + d));
}

// Pre-swizzle embed into MFMA B-fragment order, split hi/lo bf16.
__global__ void vq_prep_e(const float* __restrict__ embed, short* __restrict__ eswz) {
  int u = blockIdx.x * 256 + threadIdx.x;  // 65536 = 512ct * 2kc * 64l
  int l = u & 63, kc = (u >> 6) & 1, ct = u >> 7;
  int code = ct * 16 + (l & 15);
  int kb = kc * 32 + (l >> 4) * 8;
  const float* er = embed + (size_t)code * DIM + kb;
  short8 h8, l8;
#pragma unroll
  for (int j = 0; j < 8; ++j) {
    float v = er[j];
    unsigned short h = bf16hi(v);
    float r = v - __uint_as_float((unsigned)h << 16);
    h8[j] = (short)h;
    l8[j] = (short)bf16hi(r);
  }
  short8* dst = (short8*)eswz;
  size_t frag = (size_t)(ct * 2 + kc) * 2;
  dst[(frag + 0) * 64 + l] = h8;
  dst[(frag + 1) * 64 + l] = l8;
}

// Screen: wave = 64 rows x 512 codes. Split-bf16 MFMA (hi*hi + hi*lo + lo*hi)
// with -||e||^2/2 folded into the accumulator init. Per-lane running argmax,
// cross-lane max, margin-gated exact fp32 rescore, packed u64 atomicMax.
__global__ __launch_bounds__(256, 4) void vq_screen(
    const float* __restrict__ x, const float* __restrict__ embed,
    const short* __restrict__ eswz, const float* __restrict__ enh,
    unsigned long long* __restrict__ best) {
  const int l = threadIdx.x & 63, wid = threadIdx.x >> 6;
  const int cl = l & 15, grp = l >> 4;
  const int row0 = blockIdx.x * 256 + wid * 64;
  const int ct0 = blockIdx.y * CTS_PER_BLOCK;

  // A fragments: x rows -> hi/lo bf16, built in-register (one-time).
  short8 ahi[4][2], alo[4][2];
#pragma unroll
  for (int s = 0; s < 4; ++s) {
    const float* xr = x + (size_t)(row0 + s * 16 + cl) * DIM;
#pragma unroll
    for (int kc = 0; kc < 2; ++kc) {
      const int kb = kc * 32 + grp * 8;
#pragma unroll
      for (int j = 0; j < 8; ++j) {
        float v = xr[kb + j];
        unsigned short h = bf16hi(v);
        float r = v - __uint_as_float((unsigned)h << 16);
        ahi[s][kc][j] = (short)h;
        alo[s][kc][j] = (short)bf16hi(r);
      }
    }
  }

  const short8* eb = (const short8*)eswz;
  float bsc[4][4];
  int bidx[4][4];
#pragma unroll
  for (int s = 0; s < 4; ++s)
#pragma unroll
    for (int j = 0; j < 4; ++j) { bsc[s][j] = -3.4e38f; bidx[s][j] = 0; }

#pragma unroll 2
  for (int ct = ct0; ct < ct0 + CTS_PER_BLOCK; ++ct) {
    size_t f0 = (size_t)(ct * 2 + 0) * 128, f1 = (size_t)(ct * 2 + 1) * 128;
    short8 bh0 = eb[f0 + l], bl0 = eb[f0 + 64 + l];
    short8 bh1 = eb[f1 + l], bl1 = eb[f1 + 64 + l];
    float eh = enh[ct * 16 + cl];

    f32x4 accI = {-eh, -eh, -eh, -eh};
    f32x4 acc0 = accI, acc1 = accI, acc2 = accI, acc3 = accI;
    // k-chunk 0
    acc0 = __builtin_amdgcn_mfma_f32_16x16x32_bf16(ahi[0][0], bh0, acc0, 0, 0, 0);
    acc1 = __builtin_amdgcn_mfma_f32_16x16x32_bf16(ahi[1][0], bh0, acc1, 0, 0, 0);
    acc2 = __builtin_amdgcn_mfma_f32_16x16x32_bf16(ahi[2][0], bh0, acc2, 0, 0, 0);
    acc3 = __builtin_amdgcn_mfma_f32_16x16x32_bf16(ahi[3][0], bh0, acc3, 0, 0, 0);
    acc0 = __builtin_amdgcn_mfma_f32_16x16x32_bf16(alo[0][0], bh0, acc0, 0, 0, 0);
    acc1 = __builtin_amdgcn_mfma_f32_16x16x32_bf16(alo[1][0], bh0, acc1, 0, 0, 0);
    acc2 = __builtin_amdgcn_mfma_f32_16x16x32_bf16(alo[2][0], bh0, acc2, 0, 0, 0);
    acc3 = __builtin_amdgcn_mfma_f32_16x16x32_bf16(alo[3][0], bh0, acc3, 0, 0, 0);
    acc0 = __builtin_amdgcn_mfma_f32_16x16x32_bf16(ahi[0][0], bl0, acc0, 0, 0, 0);
    acc1 = __builtin_amdgcn_mfma_f32_16x16x32_bf16(ahi[1][0], bl0, acc1, 0, 0, 0);
    acc2 = __builtin_amdgcn_mfma_f32_16x16x32_bf16(ahi[2][0], bl0, acc2, 0, 0, 0);
    acc3 = __builtin_amdgcn_mfma_f32_16x16x32_bf16(ahi[3][0], bl0, acc3, 0, 0, 0);
    // k-chunk 1
    acc0 = __builtin_amdgcn_mfma_f32_16x16x32_bf16(ahi[0][1], bh1, acc0, 0, 0, 0);
    acc1 = __builtin_amdgcn_mfma_f32_16x16x32_bf16(ahi[1][1], bh1, acc1, 0, 0, 0);
    acc2 = __builtin_amdgcn_mfma_f32_16x16x32_bf16(ahi[2][1], bh1, acc2, 0, 0, 0);
    acc3 = __builtin_amdgcn_mfma_f32_16x16x32_bf16(ahi[3][1], bh1, acc3, 0, 0, 0);
    acc0 = __builtin_amdgcn_mfma_f32_16x16x32_bf16(alo[0][1], bh1, acc0, 0, 0, 0);
    acc1 = __builtin_amdgcn_mfma_f32_16x16x32_bf16(alo[1][1], bh1, acc1, 0, 0, 0);
    acc2 = __builtin_amdgcn_mfma_f32_16x16x32_bf16(alo[2][1], bh1, acc2, 0, 0, 0);
    acc3 = __builtin_amdgcn_mfma_f32_16x16x32_bf16(alo[3][1], bh1, acc3, 0, 0, 0);
    acc0 = __builtin_amdgcn_mfma_f32_16x16x32_bf16(ahi[0][1], bl1, acc0, 0, 0, 0);
    acc1 = __builtin_amdgcn_mfma_f32_16x16x32_bf16(ahi[1][1], bl1, acc1, 0, 0, 0);
    acc2 = __builtin_amdgcn_mfma_f32_16x16x32_bf16(ahi[2][1], bl1, acc2, 0, 0, 0);
    acc3 = __builtin_amdgcn_mfma_f32_16x16x32_bf16(ahi[3][1], bl1, acc3, 0, 0, 0);

    const int code = ct * 16 + cl;
#pragma unroll
    for (int j = 0; j < 4; ++j) {
      if (acc0[j] > bsc[0][j]) { bsc[0][j] = acc0[j]; bidx[0][j] = code; }
      if (acc1[j] > bsc[1][j]) { bsc[1][j] = acc1[j]; bidx[1][j] = code; }
      if (acc2[j] > bsc[2][j]) { bsc[2][j] = acc2[j]; bidx[2][j] = code; }
      if (acc3[j] > bsc[3][j]) { bsc[3][j] = acc3[j]; bidx[3][j] = code; }
    }
  }

  // Row max over the 16 lanes (l&15) of each group; flag lane-bests within margin.
  unsigned fmask = 0;
#pragma unroll
  for (int s = 0; s < 4; ++s)
#pragma unroll
    for (int j = 0; j < 4; ++j) {
      float m = bsc[s][j];
      m = fmaxf(m, __shfl_xor(m, 1));
      m = fmaxf(m, __shfl_xor(m, 2));
      m = fmaxf(m, __shfl_xor(m, 4));
      m = fmaxf(m, __shfl_xor(m, 8));
      if (bsc[s][j] >= m - MARGIN) fmask |= 1u << (s * 4 + j);
    }

  // Exact fp32 rescore of flagged candidates (typically 1/lane), lane-compacted.
  float exact[4][4];
#pragma unroll
  for (int s = 0; s < 4; ++s)
#pragma unroll
    for (int j = 0; j < 4; ++j) exact[s][j] = -3.4e38f;

  while (__any((int)(fmask != 0))) {
    const bool act = fmask != 0;
    const int sel = __ffs(fmask) - 1;  // -1 if none (guarded by act)
    int code = 0;
#pragma unroll
    for (int s = 0; s < 4; ++s)
#pragma unroll
      for (int j = 0; j < 4; ++j)
        code = (sel == s * 4 + j) ? bidx[s][j] : code;
    int row = act ? (row0 + (sel >> 2) * 16 + grp * 4 + (sel & 3)) : row0;
    if (!act) code = 0;
    const float4* xr = (const float4*)(x + (size_t)row * DIM);
    const float4* er = (const float4*)(embed + (size_t)code * DIM);
    float a0 = 0, a1 = 0, a2 = 0, a3 = 0, n0 = 0, n1 = 0, n2 = 0, n3 = 0;
#pragma unroll
    for (int i = 0; i < 16; ++i) {
      float4 xv = xr[i], ev = er[i];
      a0 = fmaf(xv.x, ev.x, a0); a1 = fmaf(xv.y, ev.y, a1);
      a2 = fmaf(xv.z, ev.z, a2); a3 = fmaf(xv.w, ev.w, a3);
      n0 = fmaf(ev.x, ev.x, n0); n1 = fmaf(ev.y, ev.y, n1);
      n2 = fmaf(ev.z, ev.z, n2); n3 = fmaf(ev.w, ev.w, n3);
    }
    float ex = ((a0 + a1) + (a2 + a3)) - 0.5f * ((n0 + n1) + (n2 + n3));
#pragma unroll
    for (int s = 0; s < 4; ++s)
#pragma unroll
      for (int j = 0; j < 4; ++j)
        exact[s][j] = (act && sel == s * 4 + j) ? ex : exact[s][j];
    fmask = act ? (fmask & (fmask - 1)) : 0u;
  }

  // Packed (exact score, lowest-idx) reduce across the 16-lane group; combine
  // across code-split blocks via atomicMax.
#pragma unroll
  for (int s = 0; s < 4; ++s)
#pragma unroll
    for (int j = 0; j < 4; ++j) {
      unsigned long long pk = pack_score(exact[s][j], bidx[s][j]);
      unsigned long long o;
      o = __shfl_xor(pk, 1); pk = pk > o ? pk : o;
      o = __shfl_xor(pk, 2); pk = pk > o ? pk : o;
      o = __shfl_xor(pk, 4); pk = pk > o ? pk : o;
      o = __shfl_xor(pk, 8); pk = pk > o ? pk : o;
      if (cl == 0) atomicMax(&best[row0 + s * 16 + grp * 4 + j], pk);
    }
}

// Fallback (proven round-1 path) if ws is too small for the MFMA screen.
__global__ __launch_bounds__(256, 2) void vq_score_fb(
    const float* __restrict__ x, const float* __restrict__ embed,
    const float* __restrict__ enh, unsigned long long* __restrict__ best) {
  const int row = blockIdx.x * 256 + threadIdx.x;
  const int c0 = blockIdx.y * KT_FB;
  float4 xa[16];
  const float4* xg = (const float4*)(x + (size_t)row * DIM);
#pragma unroll
  for (int i = 0; i < 16; ++i) xa[i] = xg[i];
  float bs = -3.4e38f;
  int bc = 0;
#pragma unroll 2
  for (int c = c0; c < c0 + KT_FB; ++c) {
    const float4* e4 = (const float4*)(embed + (size_t)c * DIM);
    float a0 = 0.f, a1 = 0.f, a2 = 0.f, a3 = 0.f;
#pragma unroll
    for (int i = 0; i < 16; ++i) {
      float4 ev = e4[i];
      a0 = fmaf(xa[i].x, ev.x, a0); a1 = fmaf(xa[i].y, ev.y, a1);
      a2 = fmaf(xa[i].z, ev.z, a2); a3 = fmaf(xa[i].w, ev.w, a3);
    }
    float s = ((a0 + a1) + (a2 + a3)) - enh[c];
    if (s > bs) { bs = s; bc = c; }
  }
  atomicMax(&best[row], pack_score(bs, bc));
}

__global__ void vq_finalize(const unsigned long long* __restrict__ best,
                            const float* __restrict__ embed,
                            const float* __restrict__ node_mask,
                            float* __restrict__ quant,
                            float* __restrict__ out_idx,
                            float* __restrict__ counts) {
  int gid = blockIdx.x * 256 + threadIdx.x;
  int row = gid >> 6, d = gid & 63;
  unsigned long long p = best[row];
  int idx = 0xFFFF - (int)(p & 0xFFFFull);
  quant[gid] = embed[(size_t)idx * DIM + d];
  if (d == 0) {
    out_idx[row] = (float)idx;
    atomicAdd(&counts[idx], node_mask[row]);
  }
}

__global__ void vq_perplexity(const float* __restrict__ counts, float* __restrict__ out) {
  int tid = threadIdx.x;
  float acc = 0.f;
  for (int k = tid; k < NCODES; k += 256) {
    float p = counts[k] * (1.0f / (float)ROWS);
    acc += p * logf(p + 1e-10f);
  }
#pragma unroll
  for (int off = 32; off > 0; off >>= 1) acc += __shfl_down(acc, off);
  __shared__ float red[4];
  if ((tid & 63) == 0) red[tid >> 6] = acc;
  __syncthreads();
  if (tid == 0) out[0] = expf(-((red[0] + red[1]) + (red[2] + red[3])));
}

extern "C" void kernel_launch(void* const* d_in, const int* in_sizes, int n_in,
                              void* d_out, int out_size, void* d_ws, size_t ws_size,
                              hipStream_t stream) {
  const float* x = (const float*)d_in[0];
  const float* node_mask = (const float*)d_in[1];
  const float* embed = (const float*)d_in[2];

  float* out = (float*)d_out;
  float* quant = out;
  float* out_idx = out + (size_t)ROWS * DIM;
  float* out_ppl = out_idx + ROWS;

  unsigned long long* best = (unsigned long long*)((char*)d_ws + WS_BEST);
  float* counts = (float*)((char*)d_ws + WS_COUNTS);
  float* enh = (float*)((char*)d_ws + WS_ENH);
  short* eswz = (short*)((char*)d_ws + WS_ESWZ);

  hipMemsetAsync(d_ws, 0, WS_ENH, stream);  // best + counts
  vq_enorm<<<NCODES / 256, 256, 0, stream>>>(embed, enh);
  if (ws_size >= WS_NEED) {
    vq_prep_e<<<256, 256, 0, stream>>>(embed, eswz);
    vq_screen<<<dim3(ROWS / 256, NCODES / (CTS_PER_BLOCK * 16)), 256, 0, stream>>>(
        x, embed, eswz, enh, best);
  } else {
    vq_score_fb<<<dim3(ROWS / 256, NCODES / KT_FB), 256, 0, stream>>>(x, embed, enh, best);
  }
  vq_finalize<<<ROWS * DIM / 256, 256, 0, stream>>>(best, embed, node_mask, quant, out_idx, counts);
  vq_perplexity<<<1, 256, 0, stream>>>(counts, out_ppl);
}

// Round 5
// 117.869 us; speedup vs baseline: 1.3597x; 1.3597x over previous
//
#include <hip/hip_runtime.h>

typedef __attribute__((ext_vector_type(8))) short short8;
typedef __attribute__((ext_vector_type(4))) float f32x4;

#define ROWS 16384   // B*N
#define DIM 64
#define NCODES 8192
#define MARGIN 0.008f
#define KT_FB 256
#define CTS_PER_BLOCK 32   // 512 codes per y-block

// ws layout (bytes)
#define WS_BEST   0            // 16384 * 8
#define WS_COUNTS 131072       // 8192 * 4
#define WS_ENH    163840       // 8192 * 4
#define WS_ESWZ   196608       // 8192*64*2 terms * 2B = 2097152
#define WS_NEED   2293760

__device__ __forceinline__ unsigned long long pack_score(float s, int idx) {
  unsigned u = __float_as_uint(s);
  u ^= (unsigned)((int)u >> 31) | 0x80000000u;
  return ((unsigned long long)u << 32) | (unsigned)(0xFFFF - idx);
}
__device__ __forceinline__ unsigned short bf16hi(float f) {
  unsigned u = __float_as_uint(f);
  return (unsigned short)((u + 0x7FFFu + ((u >> 16) & 1u)) >> 16);
}

__global__ void vq_enorm(const float* __restrict__ embed, float* __restrict__ enh) {
  int k = blockIdx.x * 256 + threadIdx.x;
  const float4* e4 = (const float4*)(embed + (size_t)k * DIM);
  float a = 0.f, b = 0.f, c = 0.f, d = 0.f;
#pragma unroll
  for (int i = 0; i < DIM / 4; ++i) {
    float4 v = e4[i];
    a = fmaf(v.x, v.x, a); b = fmaf(v.y, v.y, b);
    c = fmaf(v.z, v.z, c); d = fmaf(v.w, v.w, d);
  }
  enh[k] = 0.5f * ((a + b) + (c + d));
}

// Pre-swizzle embed into MFMA B-fragment order, split hi/lo bf16.
__global__ void vq_prep_e(const float* __restrict__ embed, short* __restrict__ eswz) {
  int u = blockIdx.x * 256 + threadIdx.x;  // 65536 = 512ct * 2kc * 64l
  int l = u & 63, kc = (u >> 6) & 1, ct = u >> 7;
  int code = ct * 16 + (l & 15);
  int kb = kc * 32 + (l >> 4) * 8;
  const float* er = embed + (size_t)code * DIM + kb;
  short8 h8, l8;
#pragma unroll
  for (int j = 0; j < 8; ++j) {
    float v = er[j];
    unsigned short h = bf16hi(v);
    float r = v - __uint_as_float((unsigned)h << 16);
    h8[j] = (short)h;
    l8[j] = (short)bf16hi(r);
  }
  short8* dst = (short8*)eswz;
  size_t frag = (size_t)(ct * 2 + kc) * 2;
  dst[(frag + 0) * 64 + l] = h8;
  dst[(frag + 1) * 64 + l] = l8;
}

// Screen: wave = 32 rows x 512 codes (2 row-subtiles -> ~110 VGPR, fits the
// 128-reg budget for 4 waves/SIMD; round-4's 64-row wave spilled at this bound).
// Split-bf16 MFMA (hi*hi + hi*lo + lo*hi), -||e||^2/2 folded into acc init.
// Per-lane running argmax, cross-lane max, margin-gated exact fp32 rescore,
// packed u64 atomicMax combine across code-split blocks.
__global__ __launch_bounds__(256, 4) void vq_screen(
    const float* __restrict__ x, const float* __restrict__ embed,
    const short* __restrict__ eswz, const float* __restrict__ enh,
    unsigned long long* __restrict__ best) {
  const int l = threadIdx.x & 63, wid = threadIdx.x >> 6;
  const int cl = l & 15, grp = l >> 4;
  const int row0 = blockIdx.x * 128 + wid * 32;
  const int ct0 = blockIdx.y * CTS_PER_BLOCK;

  // A fragments: x rows -> hi/lo bf16, built in-register (one-time).
  short8 ahi[2][2], alo[2][2];
#pragma unroll
  for (int s = 0; s < 2; ++s) {
    const float* xr = x + (size_t)(row0 + s * 16 + cl) * DIM;
#pragma unroll
    for (int kc = 0; kc < 2; ++kc) {
      const int kb = kc * 32 + grp * 8;
#pragma unroll
      for (int j = 0; j < 8; ++j) {
        float v = xr[kb + j];
        unsigned short h = bf16hi(v);
        float r = v - __uint_as_float((unsigned)h << 16);
        ahi[s][kc][j] = (short)h;
        alo[s][kc][j] = (short)bf16hi(r);
      }
    }
  }

  const short8* eb = (const short8*)eswz;
  float bsc[2][4];
  int bidx[2][4];
#pragma unroll
  for (int s = 0; s < 2; ++s)
#pragma unroll
    for (int j = 0; j < 4; ++j) { bsc[s][j] = -3.4e38f; bidx[s][j] = 0; }

#pragma unroll 2
  for (int ct = ct0; ct < ct0 + CTS_PER_BLOCK; ++ct) {
    size_t f0 = (size_t)(ct * 2 + 0) * 128, f1 = (size_t)(ct * 2 + 1) * 128;
    short8 bh0 = eb[f0 + l], bl0 = eb[f0 + 64 + l];
    short8 bh1 = eb[f1 + l], bl1 = eb[f1 + 64 + l];
    float eh = enh[ct * 16 + cl];

    f32x4 accI = {-eh, -eh, -eh, -eh};
    f32x4 acc0 = accI, acc1 = accI;
    // k-chunk 0
    acc0 = __builtin_amdgcn_mfma_f32_16x16x32_bf16(ahi[0][0], bh0, acc0, 0, 0, 0);
    acc1 = __builtin_amdgcn_mfma_f32_16x16x32_bf16(ahi[1][0], bh0, acc1, 0, 0, 0);
    acc0 = __builtin_amdgcn_mfma_f32_16x16x32_bf16(alo[0][0], bh0, acc0, 0, 0, 0);
    acc1 = __builtin_amdgcn_mfma_f32_16x16x32_bf16(alo[1][0], bh0, acc1, 0, 0, 0);
    acc0 = __builtin_amdgcn_mfma_f32_16x16x32_bf16(ahi[0][0], bl0, acc0, 0, 0, 0);
    acc1 = __builtin_amdgcn_mfma_f32_16x16x32_bf16(ahi[1][0], bl0, acc1, 0, 0, 0);
    // k-chunk 1
    acc0 = __builtin_amdgcn_mfma_f32_16x16x32_bf16(ahi[0][1], bh1, acc0, 0, 0, 0);
    acc1 = __builtin_amdgcn_mfma_f32_16x16x32_bf16(ahi[1][1], bh1, acc1, 0, 0, 0);
    acc0 = __builtin_amdgcn_mfma_f32_16x16x32_bf16(alo[0][1], bh1, acc0, 0, 0, 0);
    acc1 = __builtin_amdgcn_mfma_f32_16x16x32_bf16(alo[1][1], bh1, acc1, 0, 0, 0);
    acc0 = __builtin_amdgcn_mfma_f32_16x16x32_bf16(ahi[0][1], bl1, acc0, 0, 0, 0);
    acc1 = __builtin_amdgcn_mfma_f32_16x16x32_bf16(ahi[1][1], bl1, acc1, 0, 0, 0);

    const int code = ct * 16 + cl;
#pragma unroll
    for (int j = 0; j < 4; ++j) {
      if (acc0[j] > bsc[0][j]) { bsc[0][j] = acc0[j]; bidx[0][j] = code; }
      if (acc1[j] > bsc[1][j]) { bsc[1][j] = acc1[j]; bidx[1][j] = code; }
    }
  }

  // Row max over the 16 lanes (l&15) of each group; flag lane-bests within margin.
  unsigned fmask = 0;
#pragma unroll
  for (int s = 0; s < 2; ++s)
#pragma unroll
    for (int j = 0; j < 4; ++j) {
      float m = bsc[s][j];
      m = fmaxf(m, __shfl_xor(m, 1));
      m = fmaxf(m, __shfl_xor(m, 2));
      m = fmaxf(m, __shfl_xor(m, 4));
      m = fmaxf(m, __shfl_xor(m, 8));
      if (bsc[s][j] >= m - MARGIN) fmask |= 1u << (s * 4 + j);
    }

  // Exact fp32 rescore of flagged candidates (typically 1/lane), lane-compacted.
  float exact[2][4];
#pragma unroll
  for (int s = 0; s < 2; ++s)
#pragma unroll
    for (int j = 0; j < 4; ++j) exact[s][j] = -3.4e38f;

  while (__any((int)(fmask != 0))) {
    const bool act = fmask != 0;
    const int sel = __ffs(fmask) - 1;  // -1 if none (guarded by act)
    int code = 0;
#pragma unroll
    for (int s = 0; s < 2; ++s)
#pragma unroll
      for (int j = 0; j < 4; ++j)
        code = (sel == s * 4 + j) ? bidx[s][j] : code;
    int row = act ? (row0 + (sel >> 2) * 16 + grp * 4 + (sel & 3)) : row0;
    if (!act) code = 0;
    const float4* xr = (const float4*)(x + (size_t)row * DIM);
    const float4* er = (const float4*)(embed + (size_t)code * DIM);
    float a0 = 0, a1 = 0, a2 = 0, a3 = 0, n0 = 0, n1 = 0, n2 = 0, n3 = 0;
#pragma unroll
    for (int i = 0; i < 16; ++i) {
      float4 xv = xr[i], ev = er[i];
      a0 = fmaf(xv.x, ev.x, a0); a1 = fmaf(xv.y, ev.y, a1);
      a2 = fmaf(xv.z, ev.z, a2); a3 = fmaf(xv.w, ev.w, a3);
      n0 = fmaf(ev.x, ev.x, n0); n1 = fmaf(ev.y, ev.y, n1);
      n2 = fmaf(ev.z, ev.z, n2); n3 = fmaf(ev.w, ev.w, n3);
    }
    float ex = ((a0 + a1) + (a2 + a3)) - 0.5f * ((n0 + n1) + (n2 + n3));
#pragma unroll
    for (int s = 0; s < 2; ++s)
#pragma unroll
      for (int j = 0; j < 4; ++j)
        exact[s][j] = (act && sel == s * 4 + j) ? ex : exact[s][j];
    fmask = act ? (fmask & (fmask - 1)) : 0u;
  }

  // Packed (exact score, lowest-idx) reduce across the 16-lane group; combine
  // across code-split blocks via atomicMax.
#pragma unroll
  for (int s = 0; s < 2; ++s)
#pragma unroll
    for (int j = 0; j < 4; ++j) {
      unsigned long long pk = pack_score(exact[s][j], bidx[s][j]);
      unsigned long long o;
      o = __shfl_xor(pk, 1); pk = pk > o ? pk : o;
      o = __shfl_xor(pk, 2); pk = pk > o ? pk : o;
      o = __shfl_xor(pk, 4); pk = pk > o ? pk : o;
      o = __shfl_xor(pk, 8); pk = pk > o ? pk : o;
      if (cl == 0) atomicMax(&best[row0 + s * 16 + grp * 4 + j], pk);
    }
}

// Fallback (proven round-1 path) if ws is too small for the MFMA screen.
__global__ __launch_bounds__(256, 2) void vq_score_fb(
    const float* __restrict__ x, const float* __restrict__ embed,
    const float* __restrict__ enh, unsigned long long* __restrict__ best) {
  const int row = blockIdx.x * 256 + threadIdx.x;
  const int c0 = blockIdx.y * KT_FB;
  float4 xa[16];
  const float4* xg = (const float4*)(x + (size_t)row * DIM);
#pragma unroll
  for (int i = 0; i < 16; ++i) xa[i] = xg[i];
  float bs = -3.4e38f;
  int bc = 0;
#pragma unroll 2
  for (int c = c0; c < c0 + KT_FB; ++c) {
    const float4* e4 = (const float4*)(embed + (size_t)c * DIM);
    float a0 = 0.f, a1 = 0.f, a2 = 0.f, a3 = 0.f;
#pragma unroll
    for (int i = 0; i < 16; ++i) {
      float4 ev = e4[i];
      a0 = fmaf(xa[i].x, ev.x, a0); a1 = fmaf(xa[i].y, ev.y, a1);
      a2 = fmaf(xa[i].z, ev.z, a2); a3 = fmaf(xa[i].w, ev.w, a3);
    }
    float s = ((a0 + a1) + (a2 + a3)) - enh[c];
    if (s > bs) { bs = s; bc = c; }
  }
  atomicMax(&best[row], pack_score(bs, bc));
}

__global__ void vq_finalize(const unsigned long long* __restrict__ best,
                            const float* __restrict__ embed,
                            const float* __restrict__ node_mask,
                            float* __restrict__ quant,
                            float* __restrict__ out_idx,
                            float* __restrict__ counts) {
  int gid = blockIdx.x * 256 + threadIdx.x;
  int row = gid >> 6, d = gid & 63;
  unsigned long long p = best[row];
  int idx = 0xFFFF - (int)(p & 0xFFFFull);
  quant[gid] = embed[(size_t)idx * DIM + d];
  if (d == 0) {
    out_idx[row] = (float)idx;
    atomicAdd(&counts[idx], node_mask[row]);
  }
}

__global__ void vq_perplexity(const float* __restrict__ counts, float* __restrict__ out) {
  int tid = threadIdx.x;
  float acc = 0.f;
  for (int k = tid; k < NCODES; k += 256) {
    float p = counts[k] * (1.0f / (float)ROWS);
    acc += p * logf(p + 1e-10f);
  }
#pragma unroll
  for (int off = 32; off > 0; off >>= 1) acc += __shfl_down(acc, off);
  __shared__ float red[4];
  if ((tid & 63) == 0) red[tid >> 6] = acc;
  __syncthreads();
  if (tid == 0) out[0] = expf(-((red[0] + red[1]) + (red[2] + red[3])));
}

extern "C" void kernel_launch(void* const* d_in, const int* in_sizes, int n_in,
                              void* d_out, int out_size, void* d_ws, size_t ws_size,
                              hipStream_t stream) {
  const float* x = (const float*)d_in[0];
  const float* node_mask = (const float*)d_in[1];
  const float* embed = (const float*)d_in[2];

  float* out = (float*)d_out;
  float* quant = out;
  float* out_idx = out + (size_t)ROWS * DIM;
  float* out_ppl = out_idx + ROWS;

  unsigned long long* best = (unsigned long long*)((char*)d_ws + WS_BEST);
  float* counts = (float*)((char*)d_ws + WS_COUNTS);
  float* enh = (float*)((char*)d_ws + WS_ENH);
  short* eswz = (short*)((char*)d_ws + WS_ESWZ);

  hipMemsetAsync(d_ws, 0, WS_ENH, stream);  // best + counts
  vq_enorm<<<NCODES / 256, 256, 0, stream>>>(embed, enh);
  if (ws_size >= WS_NEED) {
    vq_prep_e<<<256, 256, 0, stream>>>(embed, eswz);
    vq_screen<<<dim3(ROWS / 128, NCODES / (CTS_PER_BLOCK * 16)), 256, 0, stream>>>(
        x, embed, eswz, enh, best);
  } else {
    vq_score_fb<<<dim3(ROWS / 256, NCODES / KT_FB), 256, 0, stream>>>(x, embed, enh, best);
  }
  vq_finalize<<<ROWS * DIM / 256, 256, 0, stream>>>(best, embed, node_mask, quant, out_idx, counts);
  vq_perplexity<<<1, 256, 0, stream>>>(counts, out_ppl);
}

// Round 6
// 113.858 us; speedup vs baseline: 1.4076x; 1.0352x over previous
//
#include <hip/hip_runtime.h>

typedef __attribute__((ext_vector_type(8))) short short8;
typedef __attribute__((ext_vector_type(4))) float f32x4;

#define ROWS 16384   // B*N
#define DIM 64
#define NCODES 8192
#define MARGIN 0.008f
#define KT_FB 256
#define CTS_PER_BLOCK 32   // 512 codes per y-block
#define CHUNK 4            // cts staged per LDS chunk (16 KB)

// ws layout (bytes)
#define WS_BEST   0            // 16384 * 8
#define WS_COUNTS 131072       // 8192 * 4
#define WS_ENH    163840       // 8192 * 4
#define WS_ESWZ   196608       // 8192*64*2 terms * 2B = 2097152
#define WS_NEED   2293760

__device__ __forceinline__ unsigned long long pack_score(float s, int idx) {
  unsigned u = __float_as_uint(s);
  u ^= (unsigned)((int)u >> 31) | 0x80000000u;
  return ((unsigned long long)u << 32) | (unsigned)(0xFFFF - idx);
}
__device__ __forceinline__ unsigned short bf16hi(float f) {
  unsigned u = __float_as_uint(f);
  return (unsigned short)((u + 0x7FFFu + ((u >> 16) & 1u)) >> 16);
}

__global__ void vq_enorm(const float* __restrict__ embed, float* __restrict__ enh) {
  int k = blockIdx.x * 256 + threadIdx.x;
  const float4* e4 = (const float4*)(embed + (size_t)k * DIM);
  float a = 0.f, b = 0.f, c = 0.f, d = 0.f;
#pragma unroll
  for (int i = 0; i < DIM / 4; ++i) {
    float4 v = e4[i];
    a = fmaf(v.x, v.x, a); b = fmaf(v.y, v.y, b);
    c = fmaf(v.z, v.z, c); d = fmaf(v.w, v.w, d);
  }
  enh[k] = 0.5f * ((a + b) + (c + d));
}

// Pre-swizzle embed into MFMA B-fragment order, split hi/lo bf16.
// frag index = ct*4 + kc*2 + term (term 0=hi, 1=lo); element l*16B within frag.
__global__ void vq_prep_e(const float* __restrict__ embed, short* __restrict__ eswz) {
  int u = blockIdx.x * 256 + threadIdx.x;  // 65536 = 512ct * 2kc * 64l
  int l = u & 63, kc = (u >> 6) & 1, ct = u >> 7;
  int code = ct * 16 + (l & 15);
  int kb = kc * 32 + (l >> 4) * 8;
  const float* er = embed + (size_t)code * DIM + kb;
  short8 h8, l8;
#pragma unroll
  for (int j = 0; j < 8; ++j) {
    float v = er[j];
    unsigned short h = bf16hi(v);
    float r = v - __uint_as_float((unsigned)h << 16);
    h8[j] = (short)h;
    l8[j] = (short)bf16hi(r);
  }
  short8* dst = (short8*)eswz;
  size_t frag = (size_t)ct * 4 + kc * 2;
  dst[(frag + 0) * 64 + l] = h8;
  dst[(frag + 1) * 64 + l] = l8;
}

// Screen: block = 4 waves x 32 rows, all waves share the same 512-code range.
// B-fragments staged into LDS in 4-ct chunks via global_load_lds (round 5: the
// 4 waves each re-read the same bytes from L2 -> ~200-cyc latency on the MFMA
// critical path; ds_read_b128 + fine-grained lgkmcnt removes it).
// 2 cts per iteration -> 4 independent MFMA acc chains for ILP.
__global__ __launch_bounds__(256, 4) void vq_screen(
    const float* __restrict__ x, const float* __restrict__ embed,
    const short* __restrict__ eswz, const float* __restrict__ enh,
    unsigned long long* __restrict__ best) {
  const int t = threadIdx.x;
  const int l = t & 63, wid = t >> 6;
  const int cl = l & 15, grp = l >> 4;
  const int row0 = blockIdx.x * 128 + wid * 32;
  const int ct0 = blockIdx.y * CTS_PER_BLOCK;

  __shared__ short8 bstage[CHUNK * 4 * 64];  // 16 KB

  // A fragments: x rows -> hi/lo bf16, built in-register (one-time).
  short8 ahi[2][2], alo[2][2];
#pragma unroll
  for (int s = 0; s < 2; ++s) {
    const float* xr = x + (size_t)(row0 + s * 16 + cl) * DIM;
#pragma unroll
    for (int kc = 0; kc < 2; ++kc) {
      const int kb = kc * 32 + grp * 8;
#pragma unroll
      for (int j = 0; j < 8; ++j) {
        float v = xr[kb + j];
        unsigned short h = bf16hi(v);
        float r = v - __uint_as_float((unsigned)h << 16);
        ahi[s][kc][j] = (short)h;
        alo[s][kc][j] = (short)bf16hi(r);
      }
    }
  }

  float bsc[2][4];
  int bidx[2][4];
#pragma unroll
  for (int s = 0; s < 2; ++s)
#pragma unroll
    for (int j = 0; j < 4; ++j) { bsc[s][j] = -3.4e38f; bidx[s][j] = 0; }

  for (int ch = 0; ch < CTS_PER_BLOCK / CHUNK; ++ch) {
    const int cc = ct0 + ch * CHUNK;
    // ---- stage chunk: 16 KB, 256 threads x 4 x 16 B, linear in lane ----
    {
      const char* gb = (const char*)eswz + (size_t)cc * 4 * 1024;
      char* lb = (char*)bstage;
#pragma unroll
      for (int i = 0; i < 4; ++i) {
        const int e = i * 256 + t;
        __builtin_amdgcn_global_load_lds(
            (const __attribute__((address_space(1))) void*)(gb + (size_t)e * 16),
            (__attribute__((address_space(3))) void*)(lb + e * 16), 16, 0, 0);
      }
    }
    __syncthreads();  // drains vmcnt -> LDS chunk visible to all waves

    // ---- compute 4 cts as 2 pairs, 4 independent acc chains per pair ----
#pragma unroll
    for (int p = 0; p < 2; ++p) {
      const int ctA = cc + 2 * p, ctB = ctA + 1;
      const int ciA = 2 * p, ciB = 2 * p + 1;
      float ehA = enh[ctA * 16 + cl];
      float ehB = enh[ctB * 16 + cl];
      short8 Ah0 = bstage[(ciA * 4 + 0) * 64 + l], Al0 = bstage[(ciA * 4 + 1) * 64 + l];
      short8 Ah1 = bstage[(ciA * 4 + 2) * 64 + l], Al1 = bstage[(ciA * 4 + 3) * 64 + l];
      short8 Bh0 = bstage[(ciB * 4 + 0) * 64 + l], Bl0 = bstage[(ciB * 4 + 1) * 64 + l];
      short8 Bh1 = bstage[(ciB * 4 + 2) * 64 + l], Bl1 = bstage[(ciB * 4 + 3) * 64 + l];

      f32x4 z = {0.f, 0.f, 0.f, 0.f};
      f32x4 aA0 = z, aA1 = z, aB0 = z, aB1 = z;
      // k-chunk 0, term hi*hi
      aA0 = __builtin_amdgcn_mfma_f32_16x16x32_bf16(ahi[0][0], Ah0, aA0, 0, 0, 0);
      aA1 = __builtin_amdgcn_mfma_f32_16x16x32_bf16(ahi[1][0], Ah0, aA1, 0, 0, 0);
      aB0 = __builtin_amdgcn_mfma_f32_16x16x32_bf16(ahi[0][0], Bh0, aB0, 0, 0, 0);
      aB1 = __builtin_amdgcn_mfma_f32_16x16x32_bf16(ahi[1][0], Bh0, aB1, 0, 0, 0);
      // k-chunk 0, term lo*hi
      aA0 = __builtin_amdgcn_mfma_f32_16x16x32_bf16(alo[0][0], Ah0, aA0, 0, 0, 0);
      aA1 = __builtin_amdgcn_mfma_f32_16x16x32_bf16(alo[1][0], Ah0, aA1, 0, 0, 0);
      aB0 = __builtin_amdgcn_mfma_f32_16x16x32_bf16(alo[0][0], Bh0, aB0, 0, 0, 0);
      aB1 = __builtin_amdgcn_mfma_f32_16x16x32_bf16(alo[1][0], Bh0, aB1, 0, 0, 0);
      // k-chunk 0, term hi*lo
      aA0 = __builtin_amdgcn_mfma_f32_16x16x32_bf16(ahi[0][0], Al0, aA0, 0, 0, 0);
      aA1 = __builtin_amdgcn_mfma_f32_16x16x32_bf16(ahi[1][0], Al0, aA1, 0, 0, 0);
      aB0 = __builtin_amdgcn_mfma_f32_16x16x32_bf16(ahi[0][0], Bl0, aB0, 0, 0, 0);
      aB1 = __builtin_amdgcn_mfma_f32_16x16x32_bf16(ahi[1][0], Bl0, aB1, 0, 0, 0);
      // k-chunk 1, term hi*hi
      aA0 = __builtin_amdgcn_mfma_f32_16x16x32_bf16(ahi[0][1], Ah1, aA0, 0, 0, 0);
      aA1 = __builtin_amdgcn_mfma_f32_16x16x32_bf16(ahi[1][1], Ah1, aA1, 0, 0, 0);
      aB0 = __builtin_amdgcn_mfma_f32_16x16x32_bf16(ahi[0][1], Bh1, aB0, 0, 0, 0);
      aB1 = __builtin_amdgcn_mfma_f32_16x16x32_bf16(ahi[1][1], Bh1, aB1, 0, 0, 0);
      // k-chunk 1, term lo*hi
      aA0 = __builtin_amdgcn_mfma_f32_16x16x32_bf16(alo[0][1], Ah1, aA0, 0, 0, 0);
      aA1 = __builtin_amdgcn_mfma_f32_16x16x32_bf16(alo[1][1], Ah1, aA1, 0, 0, 0);
      aB0 = __builtin_amdgcn_mfma_f32_16x16x32_bf16(alo[0][1], Bh1, aB0, 0, 0, 0);
      aB1 = __builtin_amdgcn_mfma_f32_16x16x32_bf16(alo[1][1], Bh1, aB1, 0, 0, 0);
      // k-chunk 1, term hi*lo
      aA0 = __builtin_amdgcn_mfma_f32_16x16x32_bf16(ahi[0][1], Al1, aA0, 0, 0, 0);
      aA1 = __builtin_amdgcn_mfma_f32_16x16x32_bf16(ahi[1][1], Al1, aA1, 0, 0, 0);
      aB0 = __builtin_amdgcn_mfma_f32_16x16x32_bf16(ahi[0][1], Bl1, aB0, 0, 0, 0);
      aB1 = __builtin_amdgcn_mfma_f32_16x16x32_bf16(ahi[1][1], Bl1, aB1, 0, 0, 0);

      const int codeA = ctA * 16 + cl, codeB = ctB * 16 + cl;
#pragma unroll
      for (int j = 0; j < 4; ++j) {
        float sA0 = aA0[j] - ehA, sA1 = aA1[j] - ehA;
        float sB0 = aB0[j] - ehB, sB1 = aB1[j] - ehB;
        if (sA0 > bsc[0][j]) { bsc[0][j] = sA0; bidx[0][j] = codeA; }
        if (sA1 > bsc[1][j]) { bsc[1][j] = sA1; bidx[1][j] = codeA; }
        if (sB0 > bsc[0][j]) { bsc[0][j] = sB0; bidx[0][j] = codeB; }
        if (sB1 > bsc[1][j]) { bsc[1][j] = sB1; bidx[1][j] = codeB; }
      }
    }
    __syncthreads();  // protect LDS before next chunk's stage
  }

  // Row max over the 16 lanes (l&15) of each group; flag lane-bests within margin.
  unsigned fmask = 0;
#pragma unroll
  for (int s = 0; s < 2; ++s)
#pragma unroll
    for (int j = 0; j < 4; ++j) {
      float m = bsc[s][j];
      m = fmaxf(m, __shfl_xor(m, 1));
      m = fmaxf(m, __shfl_xor(m, 2));
      m = fmaxf(m, __shfl_xor(m, 4));
      m = fmaxf(m, __shfl_xor(m, 8));
      if (bsc[s][j] >= m - MARGIN) fmask |= 1u << (s * 4 + j);
    }

  // Exact fp32 rescore of flagged candidates (typically 1/lane), lane-compacted.
  float exact[2][4];
#pragma unroll
  for (int s = 0; s < 2; ++s)
#pragma unroll
    for (int j = 0; j < 4; ++j) exact[s][j] = -3.4e38f;

  while (__any((int)(fmask != 0))) {
    const bool act = fmask != 0;
    const int sel = __ffs(fmask) - 1;  // -1 if none (guarded by act)
    int code = 0;
#pragma unroll
    for (int s = 0; s < 2; ++s)
#pragma unroll
      for (int j = 0; j < 4; ++j)
        code = (sel == s * 4 + j) ? bidx[s][j] : code;
    int row = act ? (row0 + (sel >> 2) * 16 + grp * 4 + (sel & 3)) : row0;
    if (!act) code = 0;
    const float4* xr = (const float4*)(x + (size_t)row * DIM);
    const float4* er = (const float4*)(embed + (size_t)code * DIM);
    float a0 = 0, a1 = 0, a2 = 0, a3 = 0, n0 = 0, n1 = 0, n2 = 0, n3 = 0;
#pragma unroll
    for (int i = 0; i < 16; ++i) {
      float4 xv = xr[i], ev = er[i];
      a0 = fmaf(xv.x, ev.x, a0); a1 = fmaf(xv.y, ev.y, a1);
      a2 = fmaf(xv.z, ev.z, a2); a3 = fmaf(xv.w, ev.w, a3);
      n0 = fmaf(ev.x, ev.x, n0); n1 = fmaf(ev.y, ev.y, n1);
      n2 = fmaf(ev.z, ev.z, n2); n3 = fmaf(ev.w, ev.w, n3);
    }
    float ex = ((a0 + a1) + (a2 + a3)) - 0.5f * ((n0 + n1) + (n2 + n3));
#pragma unroll
    for (int s = 0; s < 2; ++s)
#pragma unroll
      for (int j = 0; j < 4; ++j)
        exact[s][j] = (act && sel == s * 4 + j) ? ex : exact[s][j];
    fmask = act ? (fmask & (fmask - 1)) : 0u;
  }

  // Packed (exact score, lowest-idx) reduce across the 16-lane group; combine
  // across code-split blocks via atomicMax.
#pragma unroll
  for (int s = 0; s < 2; ++s)
#pragma unroll
    for (int j = 0; j < 4; ++j) {
      unsigned long long pk = pack_score(exact[s][j], bidx[s][j]);
      unsigned long long o;
      o = __shfl_xor(pk, 1); pk = pk > o ? pk : o;
      o = __shfl_xor(pk, 2); pk = pk > o ? pk : o;
      o = __shfl_xor(pk, 4); pk = pk > o ? pk : o;
      o = __shfl_xor(pk, 8); pk = pk > o ? pk : o;
      if (cl == 0) atomicMax(&best[row0 + s * 16 + grp * 4 + j], pk);
    }
}

// Fallback (proven round-1 path) if ws is too small for the MFMA screen.
__global__ __launch_bounds__(256, 2) void vq_score_fb(
    const float* __restrict__ x, const float* __restrict__ embed,
    const float* __restrict__ enh, unsigned long long* __restrict__ best) {
  const int row = blockIdx.x * 256 + threadIdx.x;
  const int c0 = blockIdx.y * KT_FB;
  float4 xa[16];
  const float4* xg = (const float4*)(x + (size_t)row * DIM);
#pragma unroll
  for (int i = 0; i < 16; ++i) xa[i] = xg[i];
  float bs = -3.4e38f;
  int bc = 0;
#pragma unroll 2
  for (int c = c0; c < c0 + KT_FB; ++c) {
    const float4* e4 = (const float4*)(embed + (size_t)c * DIM);
    float a0 = 0.f, a1 = 0.f, a2 = 0.f, a3 = 0.f;
#pragma unroll
    for (int i = 0; i < 16; ++i) {
      float4 ev = e4[i];
      a0 = fmaf(xa[i].x, ev.x, a0); a1 = fmaf(xa[i].y, ev.y, a1);
      a2 = fmaf(xa[i].z, ev.z, a2); a3 = fmaf(xa[i].w, ev.w, a3);
    }
    float s = ((a0 + a1) + (a2 + a3)) - enh[c];
    if (s > bs) { bs = s; bc = c; }
  }
  atomicMax(&best[row], pack_score(bs, bc));
}

__global__ void vq_finalize(const unsigned long long* __restrict__ best,
                            const float* __restrict__ embed,
                            const float* __restrict__ node_mask,
                            float* __restrict__ quant,
                            float* __restrict__ out_idx,
                            float* __restrict__ counts) {
  int gid = blockIdx.x * 256 + threadIdx.x;
  int row = gid >> 6, d = gid & 63;
  unsigned long long p = best[row];
  int idx = 0xFFFF - (int)(p & 0xFFFFull);
  quant[gid] = embed[(size_t)idx * DIM + d];
  if (d == 0) {
    out_idx[row] = (float)idx;
    atomicAdd(&counts[idx], node_mask[row]);
  }
}

__global__ void vq_perplexity(const float* __restrict__ counts, float* __restrict__ out) {
  int tid = threadIdx.x;
  float acc = 0.f;
  for (int k = tid; k < NCODES; k += 256) {
    float p = counts[k] * (1.0f / (float)ROWS);
    acc += p * logf(p + 1e-10f);
  }
#pragma unroll
  for (int off = 32; off > 0; off >>= 1) acc += __shfl_down(acc, off);
  __shared__ float red[4];
  if ((tid & 63) == 0) red[tid >> 6] = acc;
  __syncthreads();
  if (tid == 0) out[0] = expf(-((red[0] + red[1]) + (red[2] + red[3])));
}

extern "C" void kernel_launch(void* const* d_in, const int* in_sizes, int n_in,
                              void* d_out, int out_size, void* d_ws, size_t ws_size,
                              hipStream_t stream) {
  const float* x = (const float*)d_in[0];
  const float* node_mask = (const float*)d_in[1];
  const float* embed = (const float*)d_in[2];

  float* out = (float*)d_out;
  float* quant = out;
  float* out_idx = out + (size_t)ROWS * DIM;
  float* out_ppl = out_idx + ROWS;

  unsigned long long* best = (unsigned long long*)((char*)d_ws + WS_BEST);
  float* counts = (float*)((char*)d_ws + WS_COUNTS);
  float* enh = (float*)((char*)d_ws + WS_ENH);
  short* eswz = (short*)((char*)d_ws + WS_ESWZ);

  hipMemsetAsync(d_ws, 0, WS_ENH, stream);  // best + counts
  vq_enorm<<<NCODES / 256, 256, 0, stream>>>(embed, enh);
  if (ws_size >= WS_NEED) {
    vq_prep_e<<<256, 256, 0, stream>>>(embed, eswz);
    vq_screen<<<dim3(ROWS / 128, NCODES / (CTS_PER_BLOCK * 16)), 256, 0, stream>>>(
        x, embed, eswz, enh, best);
  } else {
    vq_score_fb<<<dim3(ROWS / 256, NCODES / KT_FB), 256, 0, stream>>>(x, embed, enh, best);
  }
  vq_finalize<<<ROWS * DIM / 256, 256, 0, stream>>>(best, embed, node_mask, quant, out_idx, counts);
  vq_perplexity<<<1, 256, 0, stream>>>(counts, out_ppl);
}